// Round 8
// baseline (580.248 us; speedup 1.0000x reference)
//
#include <hip/hip_runtime.h>
#include <math.h>

#define HID 64
#define NLAY 5
#define NFF 512

// Broadcast lane k's value to all 64 lanes via v_readlane (k is wave-uniform).
__device__ __forceinline__ float bcastf(float v, int lane) {
  return __int_as_float(__builtin_amdgcn_readlane(__float_as_int(v), lane));
}

// Wl[l] = edge_emb_w (4x64) @ edge_lin_w[l] (64x64)  -> [4][64] per layer
__global__ void prep_wl_kernel(const float* __restrict__ edge_emb_w,
                               const float* __restrict__ edge_lin_w,
                               float* __restrict__ Wl) {
  int l = blockIdx.x;
  int t = threadIdx.x;       // 256 threads = 4 j-rows x 64 dims
  int j = t >> 6;
  int d = t & 63;
  const float* ew = edge_emb_w + j * HID;
  const float* lw = edge_lin_w + l * HID * HID;
  float acc = 0.f;
#pragma unroll
  for (int k = 0; k < HID; ++k) acc = fmaf(ew[k], lw[k * HID + d], acc);
  Wl[(l * 4 + j) * HID + d] = acc;
}

// h[n][d] = vert_emb[x[n]][d]
__global__ void embed_kernel(const int* __restrict__ x,
                             const float* __restrict__ vert_emb,
                             float* __restrict__ h, int n) {
  int idx = blockIdx.x * blockDim.x + threadIdx.x;
  if (idx >= n * HID) return;
  int node = idx >> 6;
  int d = idx & 63;
  h[idx] = vert_emb[x[node] * HID + d];
}

// ---- CSR build (once per call, reused across 5 layers) ----

__global__ void zero_deg_kernel(int* __restrict__ deg, int n) {
  int i = blockIdx.x * blockDim.x + threadIdx.x;
  if (i < n) deg[i] = 0;
}

__global__ void hist_kernel(const int* __restrict__ dst, int* __restrict__ deg, int E) {
  int e = blockIdx.x * blockDim.x + threadIdx.x;
  if (e < E) atomicAdd(&deg[dst[e]], 1);
}

// Multi-block exclusive scan, phase 1: per-block sums.
__global__ void bsum_kernel(const int* __restrict__ deg, int* __restrict__ bsum, int n) {
  __shared__ int s[256];
  int t = threadIdx.x;
  int i = blockIdx.x * 256 + t;
  s[t] = (i < n) ? deg[i] : 0;
  __syncthreads();
#pragma unroll
  for (int off = 128; off > 0; off >>= 1) {
    if (t < off) s[t] += s[t + off];
    __syncthreads();
  }
  if (t == 0) bsum[blockIdx.x] = s[0];
}

// Phase 2: one block scans the block sums -> exclusive offsets.
__global__ void bscan_kernel(const int* __restrict__ bsum, int* __restrict__ boff, int nb) {
  __shared__ int s[256];
  int t = threadIdx.x;
  int v = (t < nb) ? bsum[t] : 0;
  s[t] = v;
  __syncthreads();
#pragma unroll
  for (int off = 1; off < 256; off <<= 1) {
    int u = (t >= off) ? s[t - off] : 0;
    __syncthreads();
    s[t] += u;
    __syncthreads();
  }
  if (t < nb) boff[t] = s[t] - v;   // exclusive
}

// Phase 3: per-block scan + offset -> row_ptr, cursor; last element writes row_ptr[n].
__global__ void scan3_kernel(const int* __restrict__ deg, const int* __restrict__ boff,
                             int* __restrict__ row_ptr, int* __restrict__ cursor, int n) {
  __shared__ int s[256];
  int t = threadIdx.x;
  int i = blockIdx.x * 256 + t;
  int v = (i < n) ? deg[i] : 0;
  s[t] = v;
  __syncthreads();
#pragma unroll
  for (int off = 1; off < 256; off <<= 1) {
    int u = (t >= off) ? s[t - off] : 0;
    __syncthreads();
    s[t] += u;
    __syncthreads();
  }
  if (i < n) {
    int excl = boff[blockIdx.x] + s[t] - v;
    row_ptr[i] = excl;
    cursor[i] = excl;
    if (i == n - 1) row_ptr[n] = excl + v;
  }
}

__global__ void scatter_kernel(const int* __restrict__ src,
                               const int* __restrict__ dst,
                               const float4* __restrict__ edge_attr,
                               int* __restrict__ cursor,
                               int* __restrict__ csr_src,
                               float4* __restrict__ csr_ea, int E) {
  int e = blockIdx.x * blockDim.x + threadIdx.x;
  if (e >= E) return;
  int pos = atomicAdd(&cursor[dst[e]], 1);
  csr_src[pos] = src[e];
  csr_ea[pos] = edge_attr[e];
}

// ---- gather: 1 wave per dst node, lane = dim, 16 h-loads in flight ----
// Rank-4 form: P_r[d] = sum_j ea_j[r]*h[src_j][d]; agg = sum_r Wl[r][d]*P_r[d].
// ea components are wave-uniform scalars (s_load) -> v_fma with SGPR operand;
// 4 independent accumulators break the serial dependence of the old acc chain.
// __launch_bounds__(256,8): cap 64 VGPR -> 8 waves/SIMD for latency hiding.
__global__ __launch_bounds__(256, 8)
void gather_kernel(const int* __restrict__ row_ptr,
                   const int* __restrict__ csr_src,
                   const float4* __restrict__ csr_ea,
                   const float* __restrict__ Wl,   // [4][64]
                   const float* __restrict__ h,
                   float* __restrict__ agg, int n) {
  int wid = threadIdx.x >> 6;
  int d = threadIdx.x & 63;
  int node = blockIdx.x * 4 + wid;
  if (node >= n) return;
  int beg = __builtin_amdgcn_readfirstlane(row_ptr[node]);
  int end = __builtin_amdgcn_readfirstlane(row_ptr[node + 1]);
  float P0 = 0.f, P1 = 0.f, P2 = 0.f, P3 = 0.f;
  int j = beg;
  for (; j + 16 <= end; j += 16) {
    int ss[16];
    float hh[16];
    float4 ee[16];
#pragma unroll
    for (int u = 0; u < 16; ++u) ss[u] = csr_src[j + u];
#pragma unroll
    for (int u = 0; u < 16; ++u) hh[u] = h[(size_t)ss[u] * HID + d];
#pragma unroll
    for (int u = 0; u < 16; ++u) ee[u] = csr_ea[j + u];   // uniform -> s_load
#pragma unroll
    for (int u = 0; u < 16; ++u) {
      P0 = fmaf(ee[u].x, hh[u], P0);
      P1 = fmaf(ee[u].y, hh[u], P1);
      P2 = fmaf(ee[u].z, hh[u], P2);
      P3 = fmaf(ee[u].w, hh[u], P3);
    }
  }
  for (; j + 4 <= end; j += 4) {
    int ss[4];
    float hh[4];
    float4 ee[4];
#pragma unroll
    for (int u = 0; u < 4; ++u) ss[u] = csr_src[j + u];
#pragma unroll
    for (int u = 0; u < 4; ++u) hh[u] = h[(size_t)ss[u] * HID + d];
#pragma unroll
    for (int u = 0; u < 4; ++u) ee[u] = csr_ea[j + u];
#pragma unroll
    for (int u = 0; u < 4; ++u) {
      P0 = fmaf(ee[u].x, hh[u], P0);
      P1 = fmaf(ee[u].y, hh[u], P1);
      P2 = fmaf(ee[u].z, hh[u], P2);
      P3 = fmaf(ee[u].w, hh[u], P3);
    }
  }
  for (; j < end; ++j) {
    int s0 = csr_src[j];
    float4 e0 = csr_ea[j];
    float h0 = h[(size_t)s0 * HID + d];
    P0 = fmaf(e0.x, h0, P0);
    P1 = fmaf(e0.y, h0, P1);
    P2 = fmaf(e0.z, h0, P2);
    P3 = fmaf(e0.w, h0, P3);
  }
  float acc = P0 * Wl[d];
  acc = fmaf(P1, Wl[HID + d], acc);
  acc = fmaf(P2, Wl[2 * HID + d], acc);
  acc = fmaf(P3, Wl[3 * HID + d], acc);
  agg[(size_t)node * HID + d] = acc;
}

// hn = relu(agg@rel_w + rel_b + h@root_w) + h@res_w ; 8 nodes per wave.
// Live state ~45 VGPR -> (256,8) cap of 64 is safe; 8 waves/SIMD hides weight latency.
__global__ __launch_bounds__(256, 8)
void node_kernel(const float* __restrict__ h,
                 const float* __restrict__ agg,
                 const float* __restrict__ rel_w,
                 const float* __restrict__ rel_b,
                 const float* __restrict__ root_w,
                 const float* __restrict__ res_w,
                 float* __restrict__ hn, int n) {
  int wid = threadIdx.x >> 6;
  int d = threadIdx.x & 63;
  int base = (blockIdx.x * 4 + wid) * 8;
  if (base >= n) return;
  float bd = rel_b[d];
  float hval[8], aval[8], acc2[8], accR[8];
#pragma unroll
  for (int i = 0; i < 8; ++i) {
    int node = base + i;
    bool ok = node < n;
    hval[i] = ok ? h[(size_t)node * HID + d] : 0.f;
    aval[i] = ok ? agg[(size_t)node * HID + d] : 0.f;
    acc2[i] = bd;
    accR[i] = 0.f;
  }
#pragma unroll 8
  for (int k = 0; k < HID; ++k) {
    float wr = rel_w[k * HID + d];
    float wo = root_w[k * HID + d];
    float wq = res_w[k * HID + d];
#pragma unroll
    for (int i = 0; i < 8; ++i) {
      float hk = bcastf(hval[i], k);
      float ak = bcastf(aval[i], k);
      acc2[i] = fmaf(ak, wr, acc2[i]);
      acc2[i] = fmaf(hk, wo, acc2[i]);
      accR[i] = fmaf(hk, wq, accR[i]);
    }
  }
#pragma unroll
  for (int i = 0; i < 8; ++i) {
    int node = base + i;
    if (node < n)
      hn[(size_t)node * HID + d] = fmaxf(acc2[i], 0.f) + accR[i];
  }
}

// out[n] = b2 + sum_f gelu(h[n]@w1[:,f] + b1[f]) * w2[f] ; 8 nodes per wave.
// Proven config (round 5): 104 VGPR @ (256,2), no spill, ~92 us. 16 nodes/wave
// spills (allocator caps at 128 VGPR) -- do not revisit without restructuring.
__global__ __launch_bounds__(256, 2)
void head_kernel(const float* __restrict__ h,
                 const float4* __restrict__ w1v,  // [64][128] float4
                 const float4* __restrict__ b1v,  // [128] float4
                 const float4* __restrict__ w2v,  // [128] float4
                 const float* __restrict__ b2,
                 float* __restrict__ out, int n) {
  int wid = threadIdx.x >> 6;
  int lane = threadIdx.x & 63;
  int base = (blockIdx.x * 4 + wid) * 8;
  if (base >= n) return;
  float hval[8];
#pragma unroll
  for (int i = 0; i < 8; ++i)
    hval[i] = (base + i < n) ? h[(size_t)(base + i) * HID + lane] : 0.f;
  float acc[8][8];
#pragma unroll
  for (int i = 0; i < 8; ++i)
#pragma unroll
    for (int c = 0; c < 8; ++c) acc[i][c] = 0.f;
#pragma unroll 4
  for (int k = 0; k < HID; ++k) {
    float4 wa = w1v[k * (NFF / 4) + lane * 2];
    float4 wb = w1v[k * (NFF / 4) + lane * 2 + 1];
#pragma unroll
    for (int i = 0; i < 8; ++i) {
      float hk = bcastf(hval[i], k);
      acc[i][0] = fmaf(hk, wa.x, acc[i][0]);
      acc[i][1] = fmaf(hk, wa.y, acc[i][1]);
      acc[i][2] = fmaf(hk, wa.z, acc[i][2]);
      acc[i][3] = fmaf(hk, wa.w, acc[i][3]);
      acc[i][4] = fmaf(hk, wb.x, acc[i][4]);
      acc[i][5] = fmaf(hk, wb.y, acc[i][5]);
      acc[i][6] = fmaf(hk, wb.z, acc[i][6]);
      acc[i][7] = fmaf(hk, wb.w, acc[i][7]);
    }
  }
  float4 ba = b1v[lane * 2], bb = b1v[lane * 2 + 1];
  float4 va = w2v[lane * 2], vb = w2v[lane * 2 + 1];
  float bbuf[8] = {ba.x, ba.y, ba.z, ba.w, bb.x, bb.y, bb.z, bb.w};
  float wbuf[8] = {va.x, va.y, va.z, va.w, vb.x, vb.y, vb.z, vb.w};
  float partial[8];
#pragma unroll
  for (int i = 0; i < 8; ++i) partial[i] = 0.f;
#pragma unroll
  for (int c = 0; c < 8; ++c) {
#pragma unroll
    for (int i = 0; i < 8; ++i) {
      float xv = acc[i][c] + bbuf[c];
      float g = 0.5f * xv * (1.f + erff(xv * 0.70710678118654752f)); // exact GELU
      partial[i] = fmaf(g, wbuf[c], partial[i]);
    }
  }
#pragma unroll
  for (int i = 0; i < 8; ++i) {
#pragma unroll
    for (int off = 32; off > 0; off >>= 1)
      partial[i] += __shfl_xor(partial[i], off);
  }
  if (lane == 0) {
    float bias = b2[0];
#pragma unroll
    for (int i = 0; i < 8; ++i)
      if (base + i < n) out[base + i] = partial[i] + bias;
  }
}

extern "C" void kernel_launch(void* const* d_in, const int* in_sizes, int n_in,
                              void* d_out, int out_size, void* d_ws, size_t ws_size,
                              hipStream_t stream) {
  const int*   x          = (const int*)d_in[0];
  const int*   edge_index = (const int*)d_in[1];
  const float* edge_attr  = (const float*)d_in[2];
  const float* vert_emb   = (const float*)d_in[3];
  const float* edge_emb_w = (const float*)d_in[4];
  const float* edge_lin_w = (const float*)d_in[5];
  const float* rel_w      = (const float*)d_in[6];
  const float* rel_b      = (const float*)d_in[7];
  const float* root_w     = (const float*)d_in[8];
  const float* res_w      = (const float*)d_in[9];
  const float* w1         = (const float*)d_in[10];
  const float* b1         = (const float*)d_in[11];
  const float* w2         = (const float*)d_in[12];
  const float* b2         = (const float*)d_in[13];

  const int n = in_sizes[0];
  const int E = in_sizes[2] / 4;
  const int* src = edge_index;
  const int* dst = edge_index + E;
  const int nb = (n + 255) / 256;   // scan blocks (196 for n=50000)

  // workspace layout:
  //   Wl[2048] f | hA[n*64] f | hB[n*64] f | agg[n*64] f | csr_ea[E] float4 |
  //   csr_src[E] int | row_ptr[n+1] int | cursor[n] int | deg[n] int |
  //   bsum[256] int | boff[256] int
  float* ws   = (float*)d_ws;
  float* Wl   = ws;
  float* hA   = ws + 2048;
  float* hB   = hA + (size_t)n * HID;
  float* agg  = hB + (size_t)n * HID;
  float4* csr_ea = (float4*)(agg + (size_t)n * HID);
  int* csr_src = (int*)(csr_ea + (size_t)E);
  int* row_ptr = csr_src + E;
  int* cursor  = row_ptr + (n + 1);
  int* deg     = cursor + n;
  int* bsum    = deg + n;
  int* boff    = bsum + 256;

  prep_wl_kernel<<<dim3(NLAY), dim3(256), 0, stream>>>(edge_emb_w, edge_lin_w, Wl);

  int totalHD = n * HID;
  embed_kernel<<<dim3((totalHD + 255) / 256), dim3(256), 0, stream>>>(x, vert_emb, hA, n);

  // CSR build (amortized over 5 layers)
  zero_deg_kernel<<<dim3((n + 255) / 256), dim3(256), 0, stream>>>(deg, n);
  hist_kernel<<<dim3((E + 255) / 256), dim3(256), 0, stream>>>(dst, deg, E);
  bsum_kernel<<<dim3(nb), dim3(256), 0, stream>>>(deg, bsum, n);
  bscan_kernel<<<dim3(1), dim3(256), 0, stream>>>(bsum, boff, nb);
  scan3_kernel<<<dim3(nb), dim3(256), 0, stream>>>(deg, boff, row_ptr, cursor, n);
  scatter_kernel<<<dim3((E + 255) / 256), dim3(256), 0, stream>>>(
      src, dst, (const float4*)edge_attr, cursor, csr_src, csr_ea, E);

  float* hc = hA;
  float* hx = hB;
  for (int l = 0; l < NLAY; ++l) {
    gather_kernel<<<dim3((n + 3) / 4), dim3(256), 0, stream>>>(
        row_ptr, csr_src, csr_ea, Wl + l * 4 * HID, hc, agg, n);
    node_kernel<<<dim3((n + 31) / 32), dim3(256), 0, stream>>>(
        hc, agg, rel_w + l * HID * HID, rel_b + l * HID,
        root_w + l * HID * HID, res_w + l * HID * HID, hx, n);
    float* t = hc; hc = hx; hx = t;
  }

  head_kernel<<<dim3((n + 31) / 32), dim3(256), 0, stream>>>(
      hc, (const float4*)w1, (const float4*)b1, (const float4*)w2, b2,
      (float*)d_out, n);
}

// Round 9
// 570.423 us; speedup vs baseline: 1.0172x; 1.0172x over previous
//
#include <hip/hip_runtime.h>
#include <math.h>

#define HID 64
#define NLAY 5
#define NFF 512

// Broadcast lane k's value to all 64 lanes via v_readlane (k is wave-uniform).
__device__ __forceinline__ float bcastf(float v, int lane) {
  return __int_as_float(__builtin_amdgcn_readlane(__float_as_int(v), lane));
}

// fp32 -> bf16 (round-to-nearest-even), bit trick; and back.
__device__ __forceinline__ unsigned short f2bf(float x) {
  unsigned int b = __float_as_uint(x);
  b += 0x7FFFu + ((b >> 16) & 1u);
  return (unsigned short)(b >> 16);
}
__device__ __forceinline__ float bf2f(unsigned short u) {
  return __uint_as_float((unsigned int)u << 16);
}

// Wl[l] = edge_emb_w (4x64) @ edge_lin_w[l] (64x64)  -> [4][64] per layer
__global__ void prep_wl_kernel(const float* __restrict__ edge_emb_w,
                               const float* __restrict__ edge_lin_w,
                               float* __restrict__ Wl) {
  int l = blockIdx.x;
  int t = threadIdx.x;       // 256 threads = 4 j-rows x 64 dims
  int j = t >> 6;
  int d = t & 63;
  const float* ew = edge_emb_w + j * HID;
  const float* lw = edge_lin_w + l * HID * HID;
  float acc = 0.f;
#pragma unroll
  for (int k = 0; k < HID; ++k) acc = fmaf(ew[k], lw[k * HID + d], acc);
  Wl[(l * 4 + j) * HID + d] = acc;
}

// h[n][d] = vert_emb[x[n]][d] ; also bf16 shadow for the gather path.
__global__ void embed_kernel(const int* __restrict__ x,
                             const float* __restrict__ vert_emb,
                             float* __restrict__ h,
                             unsigned short* __restrict__ h16, int n) {
  int idx = blockIdx.x * blockDim.x + threadIdx.x;
  if (idx >= n * HID) return;
  int node = idx >> 6;
  int d = idx & 63;
  float v = vert_emb[x[node] * HID + d];
  h[idx] = v;
  h16[idx] = f2bf(v);
}

// ---- CSR build (once per call, reused across 5 layers) ----

__global__ void zero_deg_kernel(int* __restrict__ deg, int n) {
  int i = blockIdx.x * blockDim.x + threadIdx.x;
  if (i < n) deg[i] = 0;
}

__global__ void hist_kernel(const int* __restrict__ dst, int* __restrict__ deg, int E) {
  int e = blockIdx.x * blockDim.x + threadIdx.x;
  if (e < E) atomicAdd(&deg[dst[e]], 1);
}

// Multi-block exclusive scan, phase 1: per-block sums.
__global__ void bsum_kernel(const int* __restrict__ deg, int* __restrict__ bsum, int n) {
  __shared__ int s[256];
  int t = threadIdx.x;
  int i = blockIdx.x * 256 + t;
  s[t] = (i < n) ? deg[i] : 0;
  __syncthreads();
#pragma unroll
  for (int off = 128; off > 0; off >>= 1) {
    if (t < off) s[t] += s[t + off];
    __syncthreads();
  }
  if (t == 0) bsum[blockIdx.x] = s[0];
}

// Phase 2: one block scans the block sums -> exclusive offsets.
__global__ void bscan_kernel(const int* __restrict__ bsum, int* __restrict__ boff, int nb) {
  __shared__ int s[256];
  int t = threadIdx.x;
  int v = (t < nb) ? bsum[t] : 0;
  s[t] = v;
  __syncthreads();
#pragma unroll
  for (int off = 1; off < 256; off <<= 1) {
    int u = (t >= off) ? s[t - off] : 0;
    __syncthreads();
    s[t] += u;
    __syncthreads();
  }
  if (t < nb) boff[t] = s[t] - v;   // exclusive
}

// Phase 3: per-block scan + offset -> row_ptr, cursor; last element writes row_ptr[n].
__global__ void scan3_kernel(const int* __restrict__ deg, const int* __restrict__ boff,
                             int* __restrict__ row_ptr, int* __restrict__ cursor, int n) {
  __shared__ int s[256];
  int t = threadIdx.x;
  int i = blockIdx.x * 256 + t;
  int v = (i < n) ? deg[i] : 0;
  s[t] = v;
  __syncthreads();
#pragma unroll
  for (int off = 1; off < 256; off <<= 1) {
    int u = (t >= off) ? s[t - off] : 0;
    __syncthreads();
    s[t] += u;
    __syncthreads();
  }
  if (i < n) {
    int excl = boff[blockIdx.x] + s[t] - v;
    row_ptr[i] = excl;
    cursor[i] = excl;
    if (i == n - 1) row_ptr[n] = excl + v;
  }
}

__global__ void scatter_kernel(const int* __restrict__ src,
                               const int* __restrict__ dst,
                               const float4* __restrict__ edge_attr,
                               int* __restrict__ cursor,
                               int* __restrict__ csr_src,
                               float4* __restrict__ csr_ea, int E) {
  int e = blockIdx.x * blockDim.x + threadIdx.x;
  if (e >= E) return;
  int pos = atomicAdd(&cursor[dst[e]], 1);
  csr_src[pos] = src[e];
  csr_ea[pos] = edge_attr[e];
}

// ---- gather: 1 wave per dst node, lane = dim, bf16 h payload ----
// Rank-4 form: P_r[d] = sum_j ea_j[r]*h[src_j][d]; agg = sum_r Wl[r][d]*P_r[d].
// h read from bf16 shadow: 128B/edge-line (1 cache line) vs 256B fp32 (2 lines).
// __launch_bounds__(256,8): cap 64 VGPR -> 8 waves/SIMD for latency hiding.
__global__ __launch_bounds__(256, 8)
void gather_kernel(const int* __restrict__ row_ptr,
                   const int* __restrict__ csr_src,
                   const float4* __restrict__ csr_ea,
                   const float* __restrict__ Wl,   // [4][64]
                   const unsigned short* __restrict__ h16,
                   float* __restrict__ agg, int n) {
  int wid = threadIdx.x >> 6;
  int d = threadIdx.x & 63;
  int node = blockIdx.x * 4 + wid;
  if (node >= n) return;
  int beg = __builtin_amdgcn_readfirstlane(row_ptr[node]);
  int end = __builtin_amdgcn_readfirstlane(row_ptr[node + 1]);
  float P0 = 0.f, P1 = 0.f, P2 = 0.f, P3 = 0.f;
  int j = beg;
  for (; j + 16 <= end; j += 16) {
    int ss[16];
    float hh[16];
    float4 ee[16];
#pragma unroll
    for (int u = 0; u < 16; ++u) ss[u] = csr_src[j + u];
#pragma unroll
    for (int u = 0; u < 16; ++u) hh[u] = bf2f(h16[(size_t)ss[u] * HID + d]);
#pragma unroll
    for (int u = 0; u < 16; ++u) ee[u] = csr_ea[j + u];   // uniform -> s_load
#pragma unroll
    for (int u = 0; u < 16; ++u) {
      P0 = fmaf(ee[u].x, hh[u], P0);
      P1 = fmaf(ee[u].y, hh[u], P1);
      P2 = fmaf(ee[u].z, hh[u], P2);
      P3 = fmaf(ee[u].w, hh[u], P3);
    }
  }
  for (; j + 4 <= end; j += 4) {
    int ss[4];
    float hh[4];
    float4 ee[4];
#pragma unroll
    for (int u = 0; u < 4; ++u) ss[u] = csr_src[j + u];
#pragma unroll
    for (int u = 0; u < 4; ++u) hh[u] = bf2f(h16[(size_t)ss[u] * HID + d]);
#pragma unroll
    for (int u = 0; u < 4; ++u) ee[u] = csr_ea[j + u];
#pragma unroll
    for (int u = 0; u < 4; ++u) {
      P0 = fmaf(ee[u].x, hh[u], P0);
      P1 = fmaf(ee[u].y, hh[u], P1);
      P2 = fmaf(ee[u].z, hh[u], P2);
      P3 = fmaf(ee[u].w, hh[u], P3);
    }
  }
  for (; j < end; ++j) {
    int s0 = csr_src[j];
    float4 e0 = csr_ea[j];
    float h0 = bf2f(h16[(size_t)s0 * HID + d]);
    P0 = fmaf(e0.x, h0, P0);
    P1 = fmaf(e0.y, h0, P1);
    P2 = fmaf(e0.z, h0, P2);
    P3 = fmaf(e0.w, h0, P3);
  }
  float acc = P0 * Wl[d];
  acc = fmaf(P1, Wl[HID + d], acc);
  acc = fmaf(P2, Wl[2 * HID + d], acc);
  acc = fmaf(P3, Wl[3 * HID + d], acc);
  agg[(size_t)node * HID + d] = acc;
}

// hn = relu(agg@rel_w + rel_b + h@root_w) + h@res_w ; 8 nodes per wave.
// Also writes the bf16 shadow of hn for the next layer's gather.
__global__ __launch_bounds__(256, 8)
void node_kernel(const float* __restrict__ h,
                 const float* __restrict__ agg,
                 const float* __restrict__ rel_w,
                 const float* __restrict__ rel_b,
                 const float* __restrict__ root_w,
                 const float* __restrict__ res_w,
                 float* __restrict__ hn,
                 unsigned short* __restrict__ hn16, int n) {
  int wid = threadIdx.x >> 6;
  int d = threadIdx.x & 63;
  int base = (blockIdx.x * 4 + wid) * 8;
  if (base >= n) return;
  float bd = rel_b[d];
  float hval[8], aval[8], acc2[8], accR[8];
#pragma unroll
  for (int i = 0; i < 8; ++i) {
    int node = base + i;
    bool ok = node < n;
    hval[i] = ok ? h[(size_t)node * HID + d] : 0.f;
    aval[i] = ok ? agg[(size_t)node * HID + d] : 0.f;
    acc2[i] = bd;
    accR[i] = 0.f;
  }
#pragma unroll 8
  for (int k = 0; k < HID; ++k) {
    float wr = rel_w[k * HID + d];
    float wo = root_w[k * HID + d];
    float wq = res_w[k * HID + d];
#pragma unroll
    for (int i = 0; i < 8; ++i) {
      float hk = bcastf(hval[i], k);
      float ak = bcastf(aval[i], k);
      acc2[i] = fmaf(ak, wr, acc2[i]);
      acc2[i] = fmaf(hk, wo, acc2[i]);
      accR[i] = fmaf(hk, wq, accR[i]);
    }
  }
#pragma unroll
  for (int i = 0; i < 8; ++i) {
    int node = base + i;
    if (node < n) {
      float v = fmaxf(acc2[i], 0.f) + accR[i];
      hn[(size_t)node * HID + d] = v;
      hn16[(size_t)node * HID + d] = f2bf(v);
    }
  }
}

// out[n] = b2 + sum_f gelu(h[n]@w1[:,f] + b1[f]) * w2[f] ; 8 nodes per wave.
// Proven config (round 5): 104 VGPR @ (256,2), no spill, ~92 us. 16 nodes/wave
// spills (allocator caps at 128 VGPR) -- do not revisit without restructuring.
__global__ __launch_bounds__(256, 2)
void head_kernel(const float* __restrict__ h,
                 const float4* __restrict__ w1v,  // [64][128] float4
                 const float4* __restrict__ b1v,  // [128] float4
                 const float4* __restrict__ w2v,  // [128] float4
                 const float* __restrict__ b2,
                 float* __restrict__ out, int n) {
  int wid = threadIdx.x >> 6;
  int lane = threadIdx.x & 63;
  int base = (blockIdx.x * 4 + wid) * 8;
  if (base >= n) return;
  float hval[8];
#pragma unroll
  for (int i = 0; i < 8; ++i)
    hval[i] = (base + i < n) ? h[(size_t)(base + i) * HID + lane] : 0.f;
  float acc[8][8];
#pragma unroll
  for (int i = 0; i < 8; ++i)
#pragma unroll
    for (int c = 0; c < 8; ++c) acc[i][c] = 0.f;
#pragma unroll 4
  for (int k = 0; k < HID; ++k) {
    float4 wa = w1v[k * (NFF / 4) + lane * 2];
    float4 wb = w1v[k * (NFF / 4) + lane * 2 + 1];
#pragma unroll
    for (int i = 0; i < 8; ++i) {
      float hk = bcastf(hval[i], k);
      acc[i][0] = fmaf(hk, wa.x, acc[i][0]);
      acc[i][1] = fmaf(hk, wa.y, acc[i][1]);
      acc[i][2] = fmaf(hk, wa.z, acc[i][2]);
      acc[i][3] = fmaf(hk, wa.w, acc[i][3]);
      acc[i][4] = fmaf(hk, wb.x, acc[i][4]);
      acc[i][5] = fmaf(hk, wb.y, acc[i][5]);
      acc[i][6] = fmaf(hk, wb.z, acc[i][6]);
      acc[i][7] = fmaf(hk, wb.w, acc[i][7]);
    }
  }
  float4 ba = b1v[lane * 2], bb = b1v[lane * 2 + 1];
  float4 va = w2v[lane * 2], vb = w2v[lane * 2 + 1];
  float bbuf[8] = {ba.x, ba.y, ba.z, ba.w, bb.x, bb.y, bb.z, bb.w};
  float wbuf[8] = {va.x, va.y, va.z, va.w, vb.x, vb.y, vb.z, vb.w};
  float partial[8];
#pragma unroll
  for (int i = 0; i < 8; ++i) partial[i] = 0.f;
#pragma unroll
  for (int c = 0; c < 8; ++c) {
#pragma unroll
    for (int i = 0; i < 8; ++i) {
      float xv = acc[i][c] + bbuf[c];
      float g = 0.5f * xv * (1.f + erff(xv * 0.70710678118654752f)); // exact GELU
      partial[i] = fmaf(g, wbuf[c], partial[i]);
    }
  }
#pragma unroll
  for (int i = 0; i < 8; ++i) {
#pragma unroll
    for (int off = 32; off > 0; off >>= 1)
      partial[i] += __shfl_xor(partial[i], off);
  }
  if (lane == 0) {
    float bias = b2[0];
#pragma unroll
    for (int i = 0; i < 8; ++i)
      if (base + i < n) out[base + i] = partial[i] + bias;
  }
}

extern "C" void kernel_launch(void* const* d_in, const int* in_sizes, int n_in,
                              void* d_out, int out_size, void* d_ws, size_t ws_size,
                              hipStream_t stream) {
  const int*   x          = (const int*)d_in[0];
  const int*   edge_index = (const int*)d_in[1];
  const float* edge_attr  = (const float*)d_in[2];
  const float* vert_emb   = (const float*)d_in[3];
  const float* edge_emb_w = (const float*)d_in[4];
  const float* edge_lin_w = (const float*)d_in[5];
  const float* rel_w      = (const float*)d_in[6];
  const float* rel_b      = (const float*)d_in[7];
  const float* root_w     = (const float*)d_in[8];
  const float* res_w      = (const float*)d_in[9];
  const float* w1         = (const float*)d_in[10];
  const float* b1         = (const float*)d_in[11];
  const float* w2         = (const float*)d_in[12];
  const float* b2         = (const float*)d_in[13];

  const int n = in_sizes[0];
  const int E = in_sizes[2] / 4;
  const int* src = edge_index;
  const int* dst = edge_index + E;
  const int nb = (n + 255) / 256;   // scan blocks (196 for n=50000)

  // workspace layout:
  //   Wl[2048] f | hA[n*64] f | hB[n*64] f | agg[n*64] f | csr_ea[E] float4 |
  //   csr_src[E] int | row_ptr[n+1] int | cursor[n] int | deg[n] int |
  //   bsum[256] int | boff[256] int | h16A[n*64] u16 | h16B[n*64] u16
  float* ws   = (float*)d_ws;
  float* Wl   = ws;
  float* hA   = ws + 2048;
  float* hB   = hA + (size_t)n * HID;
  float* agg  = hB + (size_t)n * HID;
  float4* csr_ea = (float4*)(agg + (size_t)n * HID);
  int* csr_src = (int*)(csr_ea + (size_t)E);
  int* row_ptr = csr_src + E;
  int* cursor  = row_ptr + (n + 1);
  int* deg     = cursor + n;
  int* bsum    = deg + n;
  int* boff    = bsum + 256;
  unsigned short* h16A = (unsigned short*)(boff + 256);
  unsigned short* h16B = h16A + (size_t)n * HID;

  prep_wl_kernel<<<dim3(NLAY), dim3(256), 0, stream>>>(edge_emb_w, edge_lin_w, Wl);

  int totalHD = n * HID;
  embed_kernel<<<dim3((totalHD + 255) / 256), dim3(256), 0, stream>>>(
      x, vert_emb, hA, h16A, n);

  // CSR build (amortized over 5 layers)
  zero_deg_kernel<<<dim3((n + 255) / 256), dim3(256), 0, stream>>>(deg, n);
  hist_kernel<<<dim3((E + 255) / 256), dim3(256), 0, stream>>>(dst, deg, E);
  bsum_kernel<<<dim3(nb), dim3(256), 0, stream>>>(deg, bsum, n);
  bscan_kernel<<<dim3(1), dim3(256), 0, stream>>>(bsum, boff, nb);
  scan3_kernel<<<dim3(nb), dim3(256), 0, stream>>>(deg, boff, row_ptr, cursor, n);
  scatter_kernel<<<dim3((E + 255) / 256), dim3(256), 0, stream>>>(
      src, dst, (const float4*)edge_attr, cursor, csr_src, csr_ea, E);

  float* hc = hA;
  float* hx = hB;
  unsigned short* h16c = h16A;
  unsigned short* h16x = h16B;
  for (int l = 0; l < NLAY; ++l) {
    gather_kernel<<<dim3((n + 3) / 4), dim3(256), 0, stream>>>(
        row_ptr, csr_src, csr_ea, Wl + l * 4 * HID, h16c, agg, n);
    node_kernel<<<dim3((n + 31) / 32), dim3(256), 0, stream>>>(
        hc, agg, rel_w + l * HID * HID, rel_b + l * HID,
        root_w + l * HID * HID, res_w + l * HID * HID, hx, h16x, n);
    float* t = hc; hc = hx; hx = t;
    unsigned short* t16 = h16c; h16c = h16x; h16x = t16;
  }

  head_kernel<<<dim3((n + 31) / 32), dim3(256), 0, stream>>>(
      hc, (const float4*)w1, (const float4*)b1, (const float4*)w2, b2,
      (float*)d_out, n);
}